// Round 5
// baseline (298.844 us; speedup 1.0000x reference)
//
#include <hip/hip_runtime.h>
#include <hip/hip_bf16.h>
#include <cstdint>
#include <cstddef>

typedef __attribute__((ext_vector_type(8))) short short8;
typedef __attribute__((ext_vector_type(4))) short short4v;
typedef __attribute__((ext_vector_type(4))) float floatx4;
typedef __attribute__((ext_vector_type(16))) float floatx16;
typedef unsigned short ushort_t;
typedef unsigned long long u64_t;

#define LOG2E 1.44269504088896340736f

__device__ __forceinline__ unsigned short f2bf(float f) {
    unsigned u = __float_as_uint(f);
    u += 0x7FFFu + ((u >> 16) & 1u);   // RNE
    return (unsigned short)(u >> 16);
}
__device__ __forceinline__ float bf2f(unsigned short s) {
    return __uint_as_float(((unsigned)s) << 16);
}

// ---------------------------------------------------------------------------
// gemm_h v4: hT[b][o][j] = sum_k x[b][j][k]*W[o][k]  (bf16 out, o-major).
// Block = 64 j x 256 o, 1024 threads, 16 waves.  W fp32->bf16 during LDS
// quarter-stage.  Epilogue: hT + s_src/s_dst.
// v4 addition: pack adj -> bitmask (1 bit/edge, 134MB -> 4MB) via __ballot.
// Streams coalesced at high BW here (where latency slots are idle) so attn
// never touches the 134MB int stream.
// ---------------------------------------------------------------------------
__global__ __launch_bounds__(1024) void gemm_h(const float* __restrict__ x,
                                               const float* __restrict__ W,
                                               const int* __restrict__ adj,
                                               ushort_t* __restrict__ hT,
                                               const float* __restrict__ a_src,
                                               const float* __restrict__ a_dst,
                                               float* __restrict__ s_src,
                                               float* __restrict__ s_dst,
                                               u64_t* __restrict__ adjb) {
    const int tid = threadIdx.x;
    const int w = tid >> 6, lane = tid & 63;
    const int q = lane >> 4, t16 = lane & 15;
    const int jg = w >> 2, og = w & 3;

    __shared__ ushort_t wt[256][72];   // 256 o-rows x 64 k (quarter), +8 pad
    __shared__ float sred[2][4][64];   // cross-wave s_src/s_dst partials

    const int jrow = blockIdx.x * 64 + jg * 16 + t16;
    const float* xr = x + (size_t)jrow * 256 + q * 8;
    short8 af[8];
#pragma unroll
    for (int kb = 0; kb < 8; ++kb) {
        float4 v0 = *(const float4*)(xr + kb * 32);
        float4 v1 = *(const float4*)(xr + kb * 32 + 4);
        short8 a;
        a[0] = (short)f2bf(v0.x); a[1] = (short)f2bf(v0.y);
        a[2] = (short)f2bf(v0.z); a[3] = (short)f2bf(v0.w);
        a[4] = (short)f2bf(v1.x); a[5] = (short)f2bf(v1.y);
        a[6] = (short)f2bf(v1.z); a[7] = (short)f2bf(v1.w);
        af[kb] = a;
    }

    floatx4 acc[4] = {};
#pragma unroll
    for (int kp = 0; kp < 4; ++kp) {
        if (kp) __syncthreads();
#pragma unroll
        for (int r = 0; r < 2; ++r) {
            int G = tid + 1024 * r;
            int row = G >> 3, g = G & 7;
            const float* wsrc = W + (size_t)row * 256 + kp * 64 + g * 8;
            float4 f0 = *(const float4*)(wsrc);
            float4 f1 = *(const float4*)(wsrc + 4);
            short8 wv;
            wv[0] = (short)f2bf(f0.x); wv[1] = (short)f2bf(f0.y);
            wv[2] = (short)f2bf(f0.z); wv[3] = (short)f2bf(f0.w);
            wv[4] = (short)f2bf(f1.x); wv[5] = (short)f2bf(f1.y);
            wv[6] = (short)f2bf(f1.z); wv[7] = (short)f2bf(f1.w);
            *(short8*)(&wt[row][g * 8]) = wv;
        }
        __syncthreads();
#pragma unroll
        for (int ks = 0; ks < 2; ++ks) {
#pragma unroll
            for (int ct = 0; ct < 4; ++ct) {
                short8 bf = *(const short8*)(&wt[og * 64 + ct * 16 + t16][ks * 32 + q * 8]);
                acc[ct] = __builtin_amdgcn_mfma_f32_16x16x32_bf16(af[kp * 2 + ks], bf, acc[ct], 0, 0, 0);
            }
        }
    }

    const int jbase = blockIdx.x * 64 + jg * 16 + q * 4;   // flat b*2048+j
    const int b = jbase >> 11, jj = jbase & 2047;
#pragma unroll
    for (int ct = 0; ct < 4; ++ct) {
        const int o = og * 64 + ct * 16 + t16;
        short4v sv;
        sv[0] = (short)f2bf(acc[ct][0]);
        sv[1] = (short)f2bf(acc[ct][1]);
        sv[2] = (short)f2bf(acc[ct][2]);
        sv[3] = (short)f2bf(acc[ct][3]);
        *(short4v*)(hT + ((size_t)b * 256 + o) * 2048 + jj) = sv;
    }

    float psv[4] = {}, pdv[4] = {};
#pragma unroll
    for (int ct = 0; ct < 4; ++ct) {
        const int o = og * 64 + ct * 16 + t16;
        float as = a_src[o], ad = a_dst[o];
#pragma unroll
        for (int r = 0; r < 4; ++r) {
            psv[r] = __fmaf_rn(acc[ct][r], as, psv[r]);
            pdv[r] = __fmaf_rn(acc[ct][r], ad, pdv[r]);
        }
    }
#pragma unroll
    for (int m = 1; m < 16; m <<= 1) {
#pragma unroll
        for (int r = 0; r < 4; ++r) {
            psv[r] += __shfl_xor(psv[r], m);
            pdv[r] += __shfl_xor(pdv[r], m);
        }
    }
    if (t16 == 0) {
#pragma unroll
        for (int r = 0; r < 4; ++r) {
            sred[0][og][jg * 16 + q * 4 + r] = psv[r];
            sred[1][og][jg * 16 + q * 4 + r] = pdv[r];
        }
    }
    __syncthreads();
    if (tid < 64) {
        float ss = sred[0][0][tid] + sred[0][1][tid] + sred[0][2][tid] + sred[0][3][tid];
        float dd = sred[1][0][tid] + sred[1][1][tid] + sred[1][2][tid] + sred[1][3][tid];
        s_src[blockIdx.x * 64 + tid] = ss;
        s_dst[blockIdx.x * 64 + tid] = dd;
    }

    // ---- adj bit-pack: rows [bid*64, +64), 4 rows/wave, 64 ints/ballot ----
    {
        const int row0 = blockIdx.x * 64 + w * 4;
#pragma unroll
        for (int rr = 0; rr < 4; ++rr) {
            const int* ap = adj + (size_t)(row0 + rr) * 2048 + lane;
            u64_t* bp = adjb + (size_t)(row0 + rr) * 32;
#pragma unroll 4
            for (int g = 0; g < 32; ++g) {
                u64_t mk = __ballot(ap[g * 64] != 0);
                if (lane == 0) bp[g] = mk;
            }
        }
    }
}

// ---------------------------------------------------------------------------
// attn v6: O[i][o] = (1/l_i) sum_j p[i][j] * hT[o][j],
// p = exp2(lrelu(si+sd)*log2e) masked by adj BITS.
// Block = 64 i x 256 o, grid (8 b, 32 iblk), 1024 threads (R2-v3 structure,
// measured 81.3us; v5's o-split reverted -- it duplicated adj+hT traffic
// for zero domain gain).
//
// v6 single change vs v3: adj consumed as bitmask (adjb, 4MB, L2-resident).
// Producer's 8KB/chunk global int2 stream -> one broadcast u64/row/2chunks
// + bfe per element.  p bit-identical (mask==adj!=0, same RNE/exp2 path).
// ---------------------------------------------------------------------------
__global__ __launch_bounds__(1024) void attn(const ushort_t* __restrict__ hT,
                                             const u64_t* __restrict__ adjb,
                                             const float* __restrict__ s_src,
                                             const float* __restrict__ s_dst,
                                             float* __restrict__ out) {
    const int tid = threadIdx.x;           // 0..1023
    const int w = tid >> 6;                // wave 0..15
    const int lane = tid & 63;
    const int l5 = lane & 31, hi = lane >> 5;
    const int b = blockIdx.x;
    const int i0 = blockIdx.y * 64;

    __shared__ ushort_t hts[2][256][40];   // 256 o x 32 j (+8 pad) : 40 KB
    __shared__ ushort_t ps[2][64][40];     // 64 i x 32 j (+8 pad)  : 10 KB
    __shared__ float sdl[2048];            // s_dst * log2e : 8 KB
    __shared__ float rls[64];              // row sums of p

    // stage s_dst*log2e (2 floats/thread)
    const float* sdb = s_dst + (size_t)b * 2048;
    {
        int idx = tid * 2;
        float2 v = *(const float2*)(sdb + idx);
        v.x *= LOG2E; v.y *= LOG2E;
        *(float2*)(&sdl[idx]) = v;
    }

    // p-producer mapping: i = 4w + (lane>>4), j-pair = lane&15
    const int ip = w * 4 + (lane >> 4);
    const int jp = lane & 15;
    const float si = s_src[(size_t)b * 2048 + i0 + ip] * LOG2E;
    // bitmask row: 32 u64 words (as uint2), word it covers j in [it*64,+64)
    const uint2* amr = (const uint2*)(adjb + ((size_t)b * 2048 + i0 + ip) * 32);

    // hT stage mapping: row = tid>>2, 8-j segment = tid&3 (16 B/thread)
    const int hrow = tid >> 2, hseg = tid & 3;
    const ushort_t* hTg = hT + ((size_t)b * 256 + hrow) * 2048 + hseg * 8;

    // consumer mapping: wave tile 32 i x 32 o
    const int osub = (w & 7) * 32, ih = (w >> 3) * 32;

    floatx16 acc = {};
    float lsum = 0.f;
    int4 hreg;
    uint2 amc, amcN;

    // prologue: hT chunk 0; mask words for chunks 0,1
    hreg = *(const int4*)(hTg);
    amc = amr[0];
    __syncthreads();   // sdl ready

#pragma unroll 1
    for (int it = 0; it < 32; ++it) {
        const int c = it * 2;
        // ================= even chunk c (buf 0, mask amc.x) ================
        *(int4*)(&hts[0][hrow][hseg * 8]) = hreg;
        hreg = *(const int4*)(hTg + (size_t)(c + 1) * 32);        // prefetch c+1
        amcN = amr[(it + 1 < 32) ? it + 1 : 31];                  // prefetch masks
        {
            float2 sd = *(const float2*)(&sdl[c * 32 + jp * 2]);
            unsigned m0 = (amc.x >> (jp * 2)) & 1u;
            unsigned m1 = (amc.x >> (jp * 2 + 1)) & 1u;
            float t0 = si + sd.x;
            float t1 = si + sd.y;
            float l0 = fmaxf(t0, 0.2f * t0);
            float l1 = fmaxf(t1, 0.2f * t1);
            float p0 = __builtin_amdgcn_exp2f(l0);
            float p1 = __builtin_amdgcn_exp2f(l1);
            p0 = m0 ? p0 : 0.0f;
            p1 = m1 ? p1 : 0.0f;
            unsigned short u0 = f2bf(p0);
            unsigned short u1 = f2bf(p1);
            lsum += bf2f(u0) + bf2f(u1);
            *(unsigned*)(&ps[0][ip][jp * 2]) = (unsigned)u0 | ((unsigned)u1 << 16);
        }
        __syncthreads();
#pragma unroll
        for (int ks = 0; ks < 2; ++ks) {
            short8 afr = *(const short8*)(&hts[0][osub + l5][ks * 16 + hi * 8]);
            short8 bfr = *(const short8*)(&ps[0][ih + l5][ks * 16 + hi * 8]);
            acc = __builtin_amdgcn_mfma_f32_32x32x16_bf16(afr, bfr, acc, 0, 0, 0);
        }
        // ================= odd chunk c+1 (buf 1, mask amc.y) ===============
        *(int4*)(&hts[1][hrow][hseg * 8]) = hreg;
        {   // prefetch hT chunk c+2 (clamped in-bounds at tail)
            const int nh = (c + 2 < 64) ? c + 2 : 63;
            hreg = *(const int4*)(hTg + (size_t)nh * 32);
        }
        {
            float2 sd = *(const float2*)(&sdl[(c + 1) * 32 + jp * 2]);
            unsigned m0 = (amc.y >> (jp * 2)) & 1u;
            unsigned m1 = (amc.y >> (jp * 2 + 1)) & 1u;
            float t0 = si + sd.x;
            float t1 = si + sd.y;
            float l0 = fmaxf(t0, 0.2f * t0);
            float l1 = fmaxf(t1, 0.2f * t1);
            float p0 = __builtin_amdgcn_exp2f(l0);
            float p1 = __builtin_amdgcn_exp2f(l1);
            p0 = m0 ? p0 : 0.0f;
            p1 = m1 ? p1 : 0.0f;
            unsigned short u0 = f2bf(p0);
            unsigned short u1 = f2bf(p1);
            lsum += bf2f(u0) + bf2f(u1);
            *(unsigned*)(&ps[1][ip][jp * 2]) = (unsigned)u0 | ((unsigned)u1 << 16);
        }
        __syncthreads();
#pragma unroll
        for (int ks = 0; ks < 2; ++ks) {
            short8 afr = *(const short8*)(&hts[1][osub + l5][ks * 16 + hi * 8]);
            short8 bfr = *(const short8*)(&ps[1][ih + l5][ks * 16 + hi * 8]);
            acc = __builtin_amdgcn_mfma_f32_32x32x16_bf16(afr, bfr, acc, 0, 0, 0);
        }
        amc = amcN;
    }

    // row sums: row ip's full j-range lives in its 16 jp-lanes
#pragma unroll
    for (int m = 1; m < 16; m <<= 1) lsum += __shfl_xor(lsum, m);
    if (jp == 0) rls[ip] = lsum;
    __syncthreads();

    // epilogue: D col=l5 -> i_local, row=(reg&3)+8*(reg>>2)+4*hi -> o_local
    {
        const int i = ih + l5;
        const float s = rls[i];
        const float rl = (s > 0.f) ? 1.0f / s : 0.0f;
        float* orow = out + ((size_t)b * 2048 + i0 + i) * 256 + osub;
#pragma unroll
        for (int rq = 0; rq < 4; ++rq) {
            floatx4 v;
            v[0] = acc[rq * 4 + 0] * rl;
            v[1] = acc[rq * 4 + 1] * rl;
            v[2] = acc[rq * 4 + 2] * rl;
            v[3] = acc[rq * 4 + 3] * rl;
            *(floatx4*)(orow + rq * 8 + hi * 4) = v;
        }
    }
}

extern "C" void kernel_launch(void* const* d_in, const int* in_sizes, int n_in,
                              void* d_out, int out_size, void* d_ws, size_t ws_size,
                              hipStream_t stream) {
    const float* x     = (const float*)d_in[0];
    const int*   adj   = (const int*)d_in[1];
    const float* W     = (const float*)d_in[2];
    const float* a_src = (const float*)d_in[3];
    const float* a_dst = (const float*)d_in[4];
    float* out = (float*)d_out;

    // ws: hT 8MB | s_src 64KB | s_dst 64KB | adjb 4MB  = 12.125 MB
    char* ws = (char*)d_ws;
    ushort_t* hT = (ushort_t*)ws;                                   // [0, 8M)
    float* s_src = (float*)(ws + (size_t)8 * 1024 * 1024);          // 64 KB
    float* s_dst = s_src + 16384;                                   // 64 KB
    u64_t* adjb  = (u64_t*)(s_dst + 16384);                         // 4 MB

    gemm_h<<<256, 1024, 0, stream>>>(x, W, adj, hT, a_src, a_dst, s_src, s_dst, adjb);
    attn<<<dim3(8, 32), 1024, 0, stream>>>(hT, adjb, s_src, s_dst, out);
}

// Round 6
// 277.803 us; speedup vs baseline: 1.0757x; 1.0757x over previous
//
#include <hip/hip_runtime.h>
#include <hip/hip_bf16.h>
#include <cstdint>
#include <cstddef>

typedef __attribute__((ext_vector_type(8))) short short8;
typedef __attribute__((ext_vector_type(4))) short short4v;
typedef __attribute__((ext_vector_type(4))) float floatx4;
typedef __attribute__((ext_vector_type(16))) float floatx16;
typedef unsigned short ushort_t;
typedef unsigned long long u64_t;

#define LOG2E 1.44269504088896340736f

__device__ __forceinline__ unsigned short f2bf(float f) {
    unsigned u = __float_as_uint(f);
    u += 0x7FFFu + ((u >> 16) & 1u);   // RNE
    return (unsigned short)(u >> 16);
}
__device__ __forceinline__ float bf2f(unsigned short s) {
    return __uint_as_float(((unsigned)s) << 16);
}

// ---------------------------------------------------------------------------
// gemm_h v5: h[b][j][o] = sum_k x[b][j][k]*W[o][k], output in MFMA-fragment
// layout hTf[b][os32][c][ks][lane][8]  (A-operand of 32x32x16: lane reads
// hT[o=os32*32+(lane&31)][j=c*32+ks*16+(lane>>5)*8+e] as one coalesced 16B).
// Block = 64 j x 256 o, 1024 threads.  v5 changes vs v4 (116us, all idle):
//  - x-loads: 16-line-scattered af prologue -> coalesced LDS stage/quarter
//  - adj pack: 128-deep serialized ballot chain -> int4 nibble + 4-step
//    u64 shfl_xor-OR (1KB coalesced per wave-load, unroll-4)
//  - s_src/s_dst written pre-scaled by log2e
// ---------------------------------------------------------------------------
__global__ __launch_bounds__(1024) void gemm_h(const float* __restrict__ x,
                                               const float* __restrict__ W,
                                               const int* __restrict__ adj,
                                               ushort_t* __restrict__ hTf,
                                               const float* __restrict__ a_src,
                                               const float* __restrict__ a_dst,
                                               float* __restrict__ s_src,
                                               float* __restrict__ s_dst,
                                               u64_t* __restrict__ adjb) {
    const int tid = threadIdx.x;
    const int w = tid >> 6, lane = tid & 63;
    const int q = (lane >> 4) & 3, t16 = lane & 15;
    const int jg = w >> 2, og = w & 3;

    __shared__ ushort_t wt[256][72];   // W quarter: 256 o x 64 k bf16 (+8 pad)
    __shared__ ushort_t xs[64][72];    // x quarter: 64 j x 64 k bf16 (+8 pad)
    __shared__ float sred[2][4][64];

    floatx4 acc[4] = {};
#pragma unroll
    for (int kp = 0; kp < 4; ++kp) {
        if (kp) __syncthreads();       // protect wt/xs overwrite
        // stage W quarter (fp32 -> bf16), 16 ushorts/thread
#pragma unroll
        for (int r = 0; r < 2; ++r) {
            int G = tid + 1024 * r;
            int row = G >> 3, g = G & 7;
            const float* wsrc = W + (size_t)row * 256 + kp * 64 + g * 8;
            float4 f0 = *(const float4*)(wsrc);
            float4 f1 = *(const float4*)(wsrc + 4);
            short8 wv;
            wv[0] = (short)f2bf(f0.x); wv[1] = (short)f2bf(f0.y);
            wv[2] = (short)f2bf(f0.z); wv[3] = (short)f2bf(f0.w);
            wv[4] = (short)f2bf(f1.x); wv[5] = (short)f2bf(f1.y);
            wv[6] = (short)f2bf(f1.z); wv[7] = (short)f2bf(f1.w);
            *(short8*)(&wt[row][g * 8]) = wv;
        }
        // stage x quarter (coalesced): thread -> (row = tid>>4, 4 k-cols)
        {
            int row = tid >> 4, kc = (tid & 15) * 4;
            float4 xv = *(const float4*)(x + (size_t)(blockIdx.x * 64 + row) * 256 + kp * 64 + kc);
            short4v s;
            s[0] = (short)f2bf(xv.x); s[1] = (short)f2bf(xv.y);
            s[2] = (short)f2bf(xv.z); s[3] = (short)f2bf(xv.w);
            *(short4v*)(&xs[row][kc]) = s;
        }
        __syncthreads();
#pragma unroll
        for (int ks = 0; ks < 2; ++ks) {
            short8 af = *(const short8*)(&xs[jg * 16 + t16][ks * 32 + q * 8]);
#pragma unroll
            for (int ct = 0; ct < 4; ++ct) {
                short8 bf = *(const short8*)(&wt[og * 64 + ct * 16 + t16][ks * 32 + q * 8]);
                acc[ct] = __builtin_amdgcn_mfma_f32_16x16x32_bf16(af, bf, acc[ct], 0, 0, 0);
            }
        }
    }

    // hT fragment store: lane holds acc[ct][r] = h[j=jbase+r][o=og*64+ct*16+t16]
    const int jbase = blockIdx.x * 64 + jg * 16 + q * 4;   // flat b*2048+j
    const int b = jbase >> 11, jj = jbase & 2047;
    const int c = jj >> 5, ksb = (jj >> 4) & 1, hib = (jj >> 3) & 1, e0 = jj & 7;
#pragma unroll
    for (int ct = 0; ct < 4; ++ct) {
        const int o = og * 64 + ct * 16 + t16;
        short4v sv;
        sv[0] = (short)f2bf(acc[ct][0]);
        sv[1] = (short)f2bf(acc[ct][1]);
        sv[2] = (short)f2bf(acc[ct][2]);
        sv[3] = (short)f2bf(acc[ct][3]);
        size_t eidx = (((((size_t)b * 8 + (o >> 5)) * 64 + c) * 2 + ksb) * 64
                       + hib * 32 + (o & 31)) * 8 + e0;
        *(short4v*)(hTf + eidx) = sv;
    }

    // s_src/s_dst partials (this wave's 64 o), 16-lane shuffle, scaled epilogue
    float psv[4] = {}, pdv[4] = {};
#pragma unroll
    for (int ct = 0; ct < 4; ++ct) {
        const int o = og * 64 + ct * 16 + t16;
        float as = a_src[o], ad = a_dst[o];
#pragma unroll
        for (int r = 0; r < 4; ++r) {
            psv[r] = __fmaf_rn(acc[ct][r], as, psv[r]);
            pdv[r] = __fmaf_rn(acc[ct][r], ad, pdv[r]);
        }
    }
#pragma unroll
    for (int m = 1; m < 16; m <<= 1) {
#pragma unroll
        for (int r = 0; r < 4; ++r) {
            psv[r] += __shfl_xor(psv[r], m);
            pdv[r] += __shfl_xor(pdv[r], m);
        }
    }
    if (t16 == 0) {
#pragma unroll
        for (int r = 0; r < 4; ++r) {
            sred[0][og][jg * 16 + q * 4 + r] = psv[r];
            sred[1][og][jg * 16 + q * 4 + r] = pdv[r];
        }
    }
    __syncthreads();
    if (tid < 64) {
        float ss = sred[0][0][tid] + sred[0][1][tid] + sred[0][2][tid] + sred[0][3][tid];
        float dd = sred[1][0][tid] + sred[1][1][tid] + sred[1][2][tid] + sred[1][3][tid];
        s_src[blockIdx.x * 64 + tid] = ss * LOG2E;   // pre-scaled for attn
        s_dst[blockIdx.x * 64 + tid] = dd * LOG2E;
    }

    // ---- adj bit-pack: int4 nibble + 4-step u64 shfl-OR, coalesced -------
    {
        const int g16 = lane >> 4, l16 = lane & 15;
#pragma unroll
        for (int rr = 0; rr < 4; ++rr) {
            const int row = blockIdx.x * 64 + w * 4 + rr;   // flat b*2048+i
            const int* ap = adj + (size_t)row * 2048;
#pragma unroll 4
            for (int s = 0; s < 8; ++s) {
                int4 v = *(const int4*)(ap + s * 256 + lane * 4);
                unsigned nib = (v.x != 0 ? 1u : 0u) | (v.y != 0 ? 2u : 0u) |
                               (v.z != 0 ? 4u : 0u) | (v.w != 0 ? 8u : 0u);
                u64_t val = (u64_t)nib << (l16 * 4);
                val |= __shfl_xor(val, 1);
                val |= __shfl_xor(val, 2);
                val |= __shfl_xor(val, 4);
                val |= __shfl_xor(val, 8);
                if (l16 == 0) adjb[(size_t)row * 32 + s * 4 + g16] = val;
            }
        }
    }
}

// ---------------------------------------------------------------------------
// attn v7: wave-autonomous.  O[i][o] = (1/l_i) sum_j p[i][j]*h[j][o],
// p = exp2(lrelu(si+sd)) masked by adj bits (si/sd pre-scaled by log2e).
//
// 6 rounds of evidence: NOTHING inside the bulk-sync produce/barrier/consume
// structure moves attn (conflicts, tiles, domains, operand streams all +-0);
// the only lever ever was more independent work per SIMD.  v7 deletes the
// coupling: ZERO LDS, ZERO barriers.  Each wave owns 32i x 64o, recomputes
// its own p in-registers (4x redundant VALU -- the idle pipe), reads hT as
// pre-fragmented coalesced 1KB loads (fixes v4's 32-line scatter), B-frag
// IS the 16 p-values the lane computed (layout [col=l5][k=hi*8+e]).
// Prefetch: named even/odd reg sets, ~2 chunks deep.  lsum: shfl_xor(32).
// Grid 512 blocks x 256 thr: b = bid&7 -> same-b blocks share an XCD's L2
// (hTf slice 1MB, adjb 512KB per b).
// ---------------------------------------------------------------------------
#define PEL(sv, mw, bit, pk, idx)                                            \
    {   float t_ = si + (sv);                                                \
        float l_ = fmaxf(t_, 0.2f * t_);                                     \
        float p_ = __builtin_amdgcn_exp2f(l_);                               \
        p_ = ((mw >> (bit)) & 1u) ? p_ : 0.0f;                               \
        unsigned short u_ = f2bf(p_);                                        \
        lsum += bf2f(u_);                                                    \
        pk[idx] = (short)u_; }

#define PROD(W32, S0, S1, S2, S3)                                            \
    {   unsigned mA = ((W32) >> (hi * 8)) & 0xffu;                           \
        unsigned mB = ((W32) >> (hi * 8 + 16)) & 0xffu;                      \
        PEL(S0.x, mA, 0, pa, 0) PEL(S0.y, mA, 1, pa, 1)                      \
        PEL(S0.z, mA, 2, pa, 2) PEL(S0.w, mA, 3, pa, 3)                      \
        PEL(S1.x, mA, 4, pa, 4) PEL(S1.y, mA, 5, pa, 5)                      \
        PEL(S1.z, mA, 6, pa, 6) PEL(S1.w, mA, 7, pa, 7)                      \
        PEL(S2.x, mB, 0, pb, 0) PEL(S2.y, mB, 1, pb, 1)                      \
        PEL(S2.z, mB, 2, pb, 2) PEL(S2.w, mB, 3, pb, 3)                      \
        PEL(S3.x, mB, 4, pb, 4) PEL(S3.y, mB, 5, pb, 5)                      \
        PEL(S3.z, mB, 6, pb, 6) PEL(S3.w, mB, 7, pb, 7) }

#define LOADFRAG(F00, F01, F10, F11, cc)                                     \
    F00 = *(const short8*)(fb + (size_t)(cc) * 1024);                        \
    F01 = *(const short8*)(fb + (size_t)(cc) * 1024 + 512);                  \
    F10 = *(const short8*)(fb + 65536 + (size_t)(cc) * 1024);                \
    F11 = *(const short8*)(fb + 65536 + (size_t)(cc) * 1024 + 512);

#define LOADSD(S0, S1, S2, S3, cc)                                           \
    S0 = *(const float4*)(sdb + (cc) * 32 + hi * 8);                         \
    S1 = *(const float4*)(sdb + (cc) * 32 + hi * 8 + 4);                     \
    S2 = *(const float4*)(sdb + (cc) * 32 + hi * 8 + 16);                    \
    S3 = *(const float4*)(sdb + (cc) * 32 + hi * 8 + 20);

#define MM(F00, F01, F10, F11)                                               \
    acc0 = __builtin_amdgcn_mfma_f32_32x32x16_bf16(F00, pa, acc0, 0, 0, 0);  \
    acc0 = __builtin_amdgcn_mfma_f32_32x32x16_bf16(F01, pb, acc0, 0, 0, 0);  \
    acc1 = __builtin_amdgcn_mfma_f32_32x32x16_bf16(F10, pa, acc1, 0, 0, 0);  \
    acc1 = __builtin_amdgcn_mfma_f32_32x32x16_bf16(F11, pb, acc1, 0, 0, 0);

__global__ __launch_bounds__(256) void attn(const ushort_t* __restrict__ hTf,
                                            const u64_t* __restrict__ adjb,
                                            const float* __restrict__ s_src,
                                            const float* __restrict__ s_dst,
                                            float* __restrict__ out) {
    const int tid = threadIdx.x;
    const int ot = tid >> 6;             // wave 0..3 = o-tile (64 o)
    const int lane = tid & 63;
    const int l5 = lane & 31, hi = lane >> 5;
    const int bid = blockIdx.x;
    const int b = bid & 7;               // XCD-aligned batch
    const int i0 = (bid >> 3) * 32;

    const float si = s_src[b * 2048 + i0 + l5];       // pre-scaled by log2e
    const float* sdb = s_dst + (size_t)b * 2048;      // pre-scaled
    const u64_t* amr = adjb + ((size_t)b * 2048 + i0 + l5) * 32;
    // frag base: (a,c,ks) at fb + a*65536 + c*1024 + ks*512 (elements)
    const ushort_t* fb = hTf + (size_t)(b * 8 + ot * 2) * 65536 + lane * 8;

    floatx16 acc0 = {}, acc1 = {};
    float lsum = 0.f;
    short8 fE00, fE01, fE10, fE11, fO00, fO01, fO10, fO11, pa, pb;
    float4 sE0, sE1, sE2, sE3, sO0, sO1, sO2, sO3;
    u64_t mkC, mkN;

    // prologue: chunks 0,1 + mask word 0
    mkC = amr[0];
    LOADFRAG(fE00, fE01, fE10, fE11, 0)
    LOADSD(sE0, sE1, sE2, sE3, 0)
    LOADFRAG(fO00, fO01, fO10, fO11, 1)
    LOADSD(sO0, sO1, sO2, sO3, 1)

#pragma unroll 1
    for (int t = 0; t < 32; ++t) {
        const int c = t * 2;
        mkN = amr[(t < 31) ? t + 1 : 31];
        // -------- even chunk c --------
        {
            unsigned w32 = (unsigned)mkC;
            PROD(w32, sE0, sE1, sE2, sE3)
            MM(fE00, fE01, fE10, fE11)
        }
        {
            const int nc = (c + 2 < 64) ? c + 2 : 62;
            LOADFRAG(fE00, fE01, fE10, fE11, nc)
            LOADSD(sE0, sE1, sE2, sE3, nc)
        }
        // -------- odd chunk c+1 --------
        {
            unsigned w32 = (unsigned)(mkC >> 32);
            PROD(w32, sO0, sO1, sO2, sO3)
            MM(fO00, fO01, fO10, fO11)
        }
        {
            const int nc = (c + 3 < 64) ? c + 3 : 63;
            LOADFRAG(fO00, fO01, fO10, fO11, nc)
            LOADSD(sO0, sO1, sO2, sO3, nc)
        }
        mkC = mkN;
    }

    // row sum: lane l5 covers runs {0..7,16..23}+32c, lane l5+32 the rest
    lsum += __shfl_xor(lsum, 32);
    const float rl = (lsum > 0.f) ? 1.0f / lsum : 0.0f;

    // epilogue: D col=l5 -> i, row=(reg&3)+8*(reg>>2)+4*hi -> o within 32
    float* orow = out + ((size_t)b * 2048 + i0 + l5) * 256 + ot * 64;
#pragma unroll
    for (int rq = 0; rq < 4; ++rq) {
        floatx4 v;
        v[0] = acc0[rq * 4 + 0] * rl;
        v[1] = acc0[rq * 4 + 1] * rl;
        v[2] = acc0[rq * 4 + 2] * rl;
        v[3] = acc0[rq * 4 + 3] * rl;
        *(floatx4*)(orow + rq * 8 + hi * 4) = v;
        v[0] = acc1[rq * 4 + 0] * rl;
        v[1] = acc1[rq * 4 + 1] * rl;
        v[2] = acc1[rq * 4 + 2] * rl;
        v[3] = acc1[rq * 4 + 3] * rl;
        *(floatx4*)(orow + 32 + rq * 8 + hi * 4) = v;
    }
}

extern "C" void kernel_launch(void* const* d_in, const int* in_sizes, int n_in,
                              void* d_out, int out_size, void* d_ws, size_t ws_size,
                              hipStream_t stream) {
    const float* x     = (const float*)d_in[0];
    const int*   adj   = (const int*)d_in[1];
    const float* W     = (const float*)d_in[2];
    const float* a_src = (const float*)d_in[3];
    const float* a_dst = (const float*)d_in[4];
    float* out = (float*)d_out;

    // ws: hTf 8MB | s_src 64KB | s_dst 64KB | adjb 4MB = 12.125MB (R5-proven)
    char* ws = (char*)d_ws;
    ushort_t* hTf = (ushort_t*)ws;                                  // [0, 8M)
    float* s_src = (float*)(ws + (size_t)8 * 1024 * 1024);          // 64 KB
    float* s_dst = s_src + 16384;                                   // 64 KB
    u64_t* adjb  = (u64_t*)(s_dst + 16384);                         // 4 MB

    gemm_h<<<256, 1024, 0, stream>>>(x, W, adj, hTf, a_src, a_dst, s_src, s_dst, adjb);
    attn<<<512, 256, 0, stream>>>(hTf, adjb, s_src, s_dst, out);
}

// Round 7
// 270.219 us; speedup vs baseline: 1.1059x; 1.0281x over previous
//
#include <hip/hip_runtime.h>
#include <hip/hip_bf16.h>
#include <cstdint>
#include <cstddef>

typedef __attribute__((ext_vector_type(8))) short short8;
typedef __attribute__((ext_vector_type(4))) short short4v;
typedef __attribute__((ext_vector_type(4))) float floatx4;
typedef __attribute__((ext_vector_type(16))) float floatx16;
typedef unsigned short ushort_t;
typedef unsigned long long u64_t;

#define LOG2E 1.44269504088896340736f

__device__ __forceinline__ unsigned short f2bf(float f) {
    unsigned u = __float_as_uint(f);
    u += 0x7FFFu + ((u >> 16) & 1u);   // RNE
    return (unsigned short)(u >> 16);
}
__device__ __forceinline__ float bf2f(unsigned short s) {
    return __uint_as_float(((unsigned)s) << 16);
}

// ---------------------------------------------------------------------------
// adjpack: adjb[wd] = ballot(adj[wd*64+lane] != 0).  The bit layout is
// exactly linear: word wd covers flat adj indices [wd*64, wd*64+64), bit
// position = lane.  2048 blocks x 4 waves x 64 words; each ballot reads a
// coalesced 256B.  8 blocks/CU -> full TLP; streams 134MB at ~BW.
// (R5 lesson: packing inside gemm_h's 1-block/CU grid serialized this into
// ~45us of exposed latency; dedicated kernel does it at the HBM roofline.)
// ---------------------------------------------------------------------------
__global__ __launch_bounds__(256) void adjpack(const int* __restrict__ adj,
                                               u64_t* __restrict__ adjb) {
    const int w = threadIdx.x >> 6, lane = threadIdx.x & 63;
    const size_t wbase = ((size_t)blockIdx.x * 4 + w) * 64;   // word base
    const int* ap = adj + wbase * 64 + lane;
#pragma unroll 8
    for (int t = 0; t < 64; ++t) {
        u64_t mk = __ballot(ap[(size_t)t * 64] != 0);
        if (lane == 0) adjb[wbase + t] = mk;
    }
}

// ---------------------------------------------------------------------------
// gemm_h v6: hT[b][o][j] = sum_k x[b][j][k]*W[o][k]  (bf16, o-major).
// Block = 64 j x 256 o, 1024 threads, 16 waves.  Best-of-measured parts:
//  - x staged coalesced into LDS per K-quarter (v5 fix: kills the 16-line
//    scattered af prologue)
//  - W fp32->bf16 during the same stage
//  - plain o-major hT store (v4-proven; attn v6 expects this layout)
//  - raw s_src/s_dst (attn scales by log2e itself)
//  - NO adj pack here (moved to adjpack)
// ---------------------------------------------------------------------------
__global__ __launch_bounds__(1024) void gemm_h(const float* __restrict__ x,
                                               const float* __restrict__ W,
                                               ushort_t* __restrict__ hT,
                                               const float* __restrict__ a_src,
                                               const float* __restrict__ a_dst,
                                               float* __restrict__ s_src,
                                               float* __restrict__ s_dst) {
    const int tid = threadIdx.x;
    const int w = tid >> 6, lane = tid & 63;
    const int q = (lane >> 4) & 3, t16 = lane & 15;
    const int jg = w >> 2, og = w & 3;

    __shared__ ushort_t wt[256][72];   // W quarter: 256 o x 64 k (+8 pad)
    __shared__ ushort_t xs[64][72];    // x quarter: 64 j x 64 k (+8 pad)
    __shared__ float sred[2][4][64];

    floatx4 acc[4] = {};
#pragma unroll
    for (int kp = 0; kp < 4; ++kp) {
        if (kp) __syncthreads();       // protect wt/xs overwrite
        // stage W quarter (fp32 -> bf16), 16 ushorts/thread
#pragma unroll
        for (int r = 0; r < 2; ++r) {
            int G = tid + 1024 * r;
            int row = G >> 3, g = G & 7;
            const float* wsrc = W + (size_t)row * 256 + kp * 64 + g * 8;
            float4 f0 = *(const float4*)(wsrc);
            float4 f1 = *(const float4*)(wsrc + 4);
            short8 wv;
            wv[0] = (short)f2bf(f0.x); wv[1] = (short)f2bf(f0.y);
            wv[2] = (short)f2bf(f0.z); wv[3] = (short)f2bf(f0.w);
            wv[4] = (short)f2bf(f1.x); wv[5] = (short)f2bf(f1.y);
            wv[6] = (short)f2bf(f1.z); wv[7] = (short)f2bf(f1.w);
            *(short8*)(&wt[row][g * 8]) = wv;
        }
        // stage x quarter (coalesced): thread -> (row = tid>>4, 4 k-cols)
        {
            int row = tid >> 4, kc = (tid & 15) * 4;
            float4 xv = *(const float4*)(x + (size_t)(blockIdx.x * 64 + row) * 256 + kp * 64 + kc);
            short4v s;
            s[0] = (short)f2bf(xv.x); s[1] = (short)f2bf(xv.y);
            s[2] = (short)f2bf(xv.z); s[3] = (short)f2bf(xv.w);
            *(short4v*)(&xs[row][kc]) = s;
        }
        __syncthreads();
#pragma unroll
        for (int ks = 0; ks < 2; ++ks) {
            short8 af = *(const short8*)(&xs[jg * 16 + t16][ks * 32 + q * 8]);
#pragma unroll
            for (int ct = 0; ct < 4; ++ct) {
                short8 bf = *(const short8*)(&wt[og * 64 + ct * 16 + t16][ks * 32 + q * 8]);
                acc[ct] = __builtin_amdgcn_mfma_f32_16x16x32_bf16(af, bf, acc[ct], 0, 0, 0);
            }
        }
    }

    // hT store: D col=t16 -> o_local, row=q*4+r -> j_local  (o-major layout)
    const int jbase = blockIdx.x * 64 + jg * 16 + q * 4;   // flat b*2048+j
    const int b = jbase >> 11, jj = jbase & 2047;
#pragma unroll
    for (int ct = 0; ct < 4; ++ct) {
        const int o = og * 64 + ct * 16 + t16;
        short4v sv;
        sv[0] = (short)f2bf(acc[ct][0]);
        sv[1] = (short)f2bf(acc[ct][1]);
        sv[2] = (short)f2bf(acc[ct][2]);
        sv[3] = (short)f2bf(acc[ct][3]);
        *(short4v*)(hT + ((size_t)b * 256 + o) * 2048 + jj) = sv;
    }

    // s_src/s_dst partials (this wave's 64 o), 16-lane shuffle, raw values
    float psv[4] = {}, pdv[4] = {};
#pragma unroll
    for (int ct = 0; ct < 4; ++ct) {
        const int o = og * 64 + ct * 16 + t16;
        float as = a_src[o], ad = a_dst[o];
#pragma unroll
        for (int r = 0; r < 4; ++r) {
            psv[r] = __fmaf_rn(acc[ct][r], as, psv[r]);
            pdv[r] = __fmaf_rn(acc[ct][r], ad, pdv[r]);
        }
    }
#pragma unroll
    for (int m = 1; m < 16; m <<= 1) {
#pragma unroll
        for (int r = 0; r < 4; ++r) {
            psv[r] += __shfl_xor(psv[r], m);
            pdv[r] += __shfl_xor(pdv[r], m);
        }
    }
    if (t16 == 0) {
#pragma unroll
        for (int r = 0; r < 4; ++r) {
            sred[0][og][jg * 16 + q * 4 + r] = psv[r];
            sred[1][og][jg * 16 + q * 4 + r] = pdv[r];
        }
    }
    __syncthreads();
    if (tid < 64) {
        float ss = sred[0][0][tid] + sred[0][1][tid] + sred[0][2][tid] + sred[0][3][tid];
        float dd = sred[1][0][tid] + sred[1][1][tid] + sred[1][2][tid] + sred[1][3][tid];
        s_src[blockIdx.x * 64 + tid] = ss;
        s_dst[blockIdx.x * 64 + tid] = dd;
    }
}

// ---------------------------------------------------------------------------
// attn v8 == R5's attn v6 VERBATIM (bitmask + LDS-staged hT, 1 barrier/chunk;
// harness-passed; fill-corrected fit puts it at ~20-25us -- the R5 bitmask
// change was the big win, masked then by the in-gemm pack regression).
// v7's zero-LDS design reverted: 4x L2 read amplification (512MB at 2
// waves/SIMD) made it slower, not faster.
// ---------------------------------------------------------------------------
__global__ __launch_bounds__(1024) void attn(const ushort_t* __restrict__ hT,
                                             const u64_t* __restrict__ adjb,
                                             const float* __restrict__ s_src,
                                             const float* __restrict__ s_dst,
                                             float* __restrict__ out) {
    const int tid = threadIdx.x;           // 0..1023
    const int w = tid >> 6;                // wave 0..15
    const int lane = tid & 63;
    const int l5 = lane & 31, hi = lane >> 5;
    const int b = blockIdx.x;
    const int i0 = blockIdx.y * 64;

    __shared__ ushort_t hts[2][256][40];   // 256 o x 32 j (+8 pad) : 40 KB
    __shared__ ushort_t ps[2][64][40];     // 64 i x 32 j (+8 pad)  : 10 KB
    __shared__ float sdl[2048];            // s_dst * log2e : 8 KB
    __shared__ float rls[64];              // row sums of p

    // stage s_dst*log2e (2 floats/thread)
    const float* sdb = s_dst + (size_t)b * 2048;
    {
        int idx = tid * 2;
        float2 v = *(const float2*)(sdb + idx);
        v.x *= LOG2E; v.y *= LOG2E;
        *(float2*)(&sdl[idx]) = v;
    }

    // p-producer mapping: i = 4w + (lane>>4), j-pair = lane&15
    const int ip = w * 4 + (lane >> 4);
    const int jp = lane & 15;
    const float si = s_src[(size_t)b * 2048 + i0 + ip] * LOG2E;
    // bitmask row: 32 u64 words (as uint2), word it covers j in [it*64,+64)
    const uint2* amr = (const uint2*)(adjb + ((size_t)b * 2048 + i0 + ip) * 32);

    // hT stage mapping: row = tid>>2, 8-j segment = tid&3 (16 B/thread)
    const int hrow = tid >> 2, hseg = tid & 3;
    const ushort_t* hTg = hT + ((size_t)b * 256 + hrow) * 2048 + hseg * 8;

    // consumer mapping: wave tile 32 i x 32 o
    const int osub = (w & 7) * 32, ih = (w >> 3) * 32;

    floatx16 acc = {};
    float lsum = 0.f;
    int4 hreg;
    uint2 amc, amcN;

    // prologue: hT chunk 0; mask words for chunks 0,1
    hreg = *(const int4*)(hTg);
    amc = amr[0];
    __syncthreads();   // sdl ready

#pragma unroll 1
    for (int it = 0; it < 32; ++it) {
        const int c = it * 2;
        // ================= even chunk c (buf 0, mask amc.x) ================
        *(int4*)(&hts[0][hrow][hseg * 8]) = hreg;
        hreg = *(const int4*)(hTg + (size_t)(c + 1) * 32);        // prefetch c+1
        amcN = amr[(it + 1 < 32) ? it + 1 : 31];                  // prefetch masks
        {
            float2 sd = *(const float2*)(&sdl[c * 32 + jp * 2]);
            unsigned m0 = (amc.x >> (jp * 2)) & 1u;
            unsigned m1 = (amc.x >> (jp * 2 + 1)) & 1u;
            float t0 = si + sd.x;
            float t1 = si + sd.y;
            float l0 = fmaxf(t0, 0.2f * t0);
            float l1 = fmaxf(t1, 0.2f * t1);
            float p0 = __builtin_amdgcn_exp2f(l0);
            float p1 = __builtin_amdgcn_exp2f(l1);
            p0 = m0 ? p0 : 0.0f;
            p1 = m1 ? p1 : 0.0f;
            unsigned short u0 = f2bf(p0);
            unsigned short u1 = f2bf(p1);
            lsum += bf2f(u0) + bf2f(u1);
            *(unsigned*)(&ps[0][ip][jp * 2]) = (unsigned)u0 | ((unsigned)u1 << 16);
        }
        __syncthreads();
#pragma unroll
        for (int ks = 0; ks < 2; ++ks) {
            short8 afr = *(const short8*)(&hts[0][osub + l5][ks * 16 + hi * 8]);
            short8 bfr = *(const short8*)(&ps[0][ih + l5][ks * 16 + hi * 8]);
            acc = __builtin_amdgcn_mfma_f32_32x32x16_bf16(afr, bfr, acc, 0, 0, 0);
        }
        // ================= odd chunk c+1 (buf 1, mask amc.y) ===============
        *(int4*)(&hts[1][hrow][hseg * 8]) = hreg;
        {   // prefetch hT chunk c+2 (clamped in-bounds at tail)
            const int nh = (c + 2 < 64) ? c + 2 : 63;
            hreg = *(const int4*)(hTg + (size_t)nh * 32);
        }
        {
            float2 sd = *(const float2*)(&sdl[(c + 1) * 32 + jp * 2]);
            unsigned m0 = (amc.y >> (jp * 2)) & 1u;
            unsigned m1 = (amc.y >> (jp * 2 + 1)) & 1u;
            float t0 = si + sd.x;
            float t1 = si + sd.y;
            float l0 = fmaxf(t0, 0.2f * t0);
            float l1 = fmaxf(t1, 0.2f * t1);
            float p0 = __builtin_amdgcn_exp2f(l0);
            float p1 = __builtin_amdgcn_exp2f(l1);
            p0 = m0 ? p0 : 0.0f;
            p1 = m1 ? p1 : 0.0f;
            unsigned short u0 = f2bf(p0);
            unsigned short u1 = f2bf(p1);
            lsum += bf2f(u0) + bf2f(u1);
            *(unsigned*)(&ps[1][ip][jp * 2]) = (unsigned)u0 | ((unsigned)u1 << 16);
        }
        __syncthreads();
#pragma unroll
        for (int ks = 0; ks < 2; ++ks) {
            short8 afr = *(const short8*)(&hts[1][osub + l5][ks * 16 + hi * 8]);
            short8 bfr = *(const short8*)(&ps[1][ih + l5][ks * 16 + hi * 8]);
            acc = __builtin_amdgcn_mfma_f32_32x32x16_bf16(afr, bfr, acc, 0, 0, 0);
        }
        amc = amcN;
    }

    // row sums: row ip's full j-range lives in its 16 jp-lanes
#pragma unroll
    for (int m = 1; m < 16; m <<= 1) lsum += __shfl_xor(lsum, m);
    if (jp == 0) rls[ip] = lsum;
    __syncthreads();

    // epilogue: D col=l5 -> i_local, row=(reg&3)+8*(reg>>2)+4*hi -> o_local
    {
        const int i = ih + l5;
        const float s = rls[i];
        const float rl = (s > 0.f) ? 1.0f / s : 0.0f;
        float* orow = out + ((size_t)b * 2048 + i0 + i) * 256 + osub;
#pragma unroll
        for (int rq = 0; rq < 4; ++rq) {
            floatx4 v;
            v[0] = acc[rq * 4 + 0] * rl;
            v[1] = acc[rq * 4 + 1] * rl;
            v[2] = acc[rq * 4 + 2] * rl;
            v[3] = acc[rq * 4 + 3] * rl;
            *(floatx4*)(orow + rq * 8 + hi * 4) = v;
        }
    }
}

extern "C" void kernel_launch(void* const* d_in, const int* in_sizes, int n_in,
                              void* d_out, int out_size, void* d_ws, size_t ws_size,
                              hipStream_t stream) {
    const float* x     = (const float*)d_in[0];
    const int*   adj   = (const int*)d_in[1];
    const float* W     = (const float*)d_in[2];
    const float* a_src = (const float*)d_in[3];
    const float* a_dst = (const float*)d_in[4];
    float* out = (float*)d_out;

    // ws: hT 8MB | s_src 64KB | s_dst 64KB | adjb 4MB = 12.125MB (R5-proven)
    char* ws = (char*)d_ws;
    ushort_t* hT = (ushort_t*)ws;                                   // [0, 8M)
    float* s_src = (float*)(ws + (size_t)8 * 1024 * 1024);          // 64 KB
    float* s_dst = s_src + 16384;                                   // 64 KB
    u64_t* adjb  = (u64_t*)(s_dst + 16384);                         // 4 MB

    adjpack<<<2048, 256, 0, stream>>>(adj, adjb);
    gemm_h<<<256, 1024, 0, stream>>>(x, W, hT, a_src, a_dst, s_src, s_dst);
    attn<<<dim3(8, 32), 1024, 0, stream>>>(hT, adjb, s_src, s_dst, out);
}

// Round 8
// 264.922 us; speedup vs baseline: 1.1280x; 1.0200x over previous
//
#include <hip/hip_runtime.h>
#include <hip/hip_bf16.h>
#include <cstdint>
#include <cstddef>

typedef __attribute__((ext_vector_type(8))) short short8;
typedef __attribute__((ext_vector_type(4))) short short4v;
typedef __attribute__((ext_vector_type(4))) float floatx4;
typedef __attribute__((ext_vector_type(16))) float floatx16;
typedef unsigned short ushort_t;
typedef unsigned long long u64_t;

#define LOG2E 1.44269504088896340736f

__device__ __forceinline__ unsigned short f2bf(float f) {
    unsigned u = __float_as_uint(f);
    u += 0x7FFFu + ((u >> 16) & 1u);   // RNE
    return (unsigned short)(u >> 16);
}
__device__ __forceinline__ float bf2f(unsigned short s) {
    return __uint_as_float(((unsigned)s) << 16);
}

// ---------------------------------------------------------------------------
// prep: fused gemm_h + adjpack, 768 blocks x 1024 threads, 2 blocks/CU
// (launch_bounds(1024,8) caps VGPR at 64 -> 32 waves/CU).
//
// R7 lesson: adjpack(21us floor) + gemm(10us floor) measured ~84us COMBINED
// as back-to-back dispatches -- each runs alone, bulk-synchronous, paying
// full exposed latency with nothing co-resident.  Fusing them puts an
// adj-streaming block next to every barrier-bound gemm block on each CU:
// while gemm drains, adjpack issues, and vice versa.
//
// blocks [0,256):   gemm_h v6 body verbatim (R7-passing): 64j x 256o tile,
//                   x+W staged coalesced into LDS per K-quarter, o-major hT
//                   store, s_src/s_dst via cross-wave LDS reduction.
// blocks [256,768): adjpack: 16 waves/block, wave packs 64 u64 words via
//                   ballot (coalesced 256B reads; bit l of word wd =
//                   adj[wd*64+l] != 0; layout exactly linear).
// ---------------------------------------------------------------------------
__global__ __launch_bounds__(1024, 8) void prep(const float* __restrict__ x,
                                                const float* __restrict__ W,
                                                const int* __restrict__ adj,
                                                ushort_t* __restrict__ hT,
                                                const float* __restrict__ a_src,
                                                const float* __restrict__ a_dst,
                                                float* __restrict__ s_src,
                                                float* __restrict__ s_dst,
                                                u64_t* __restrict__ adjb) {
    __shared__ ushort_t wt[256][72];   // W quarter: 256 o x 64 k (+8 pad)
    __shared__ ushort_t xs[64][72];    // x quarter: 64 j x 64 k (+8 pad)
    __shared__ float sred[2][4][64];

    const int tid = threadIdx.x;
    const int w = tid >> 6, lane = tid & 63;

    if (blockIdx.x >= 256) {
        // ---------------- adjpack half (512 blocks x 16 waves) ------------
        const size_t wbase = ((size_t)(blockIdx.x - 256) * 16 + w) * 64;
        const int* ap = adj + wbase * 64 + lane;
        u64_t* bp = adjb + wbase;
#pragma unroll 8
        for (int t = 0; t < 64; ++t) {
            u64_t mk = __ballot(ap[(size_t)t * 64] != 0);
            if (lane == 0) bp[t] = mk;
        }
        return;
    }

    // ------------------- gemm half (256 blocks, R7 body) ------------------
    const int bid = blockIdx.x;
    const int q = (lane >> 4) & 3, t16 = lane & 15;
    const int jg = w >> 2, og = w & 3;

    floatx4 acc[4] = {};
#pragma unroll
    for (int kp = 0; kp < 4; ++kp) {
        if (kp) __syncthreads();       // protect wt/xs overwrite
        // stage W quarter (fp32 -> bf16), 16 ushorts/thread
#pragma unroll
        for (int r = 0; r < 2; ++r) {
            int G = tid + 1024 * r;
            int row = G >> 3, g = G & 7;
            const float* wsrc = W + (size_t)row * 256 + kp * 64 + g * 8;
            float4 f0 = *(const float4*)(wsrc);
            float4 f1 = *(const float4*)(wsrc + 4);
            short8 wv;
            wv[0] = (short)f2bf(f0.x); wv[1] = (short)f2bf(f0.y);
            wv[2] = (short)f2bf(f0.z); wv[3] = (short)f2bf(f0.w);
            wv[4] = (short)f2bf(f1.x); wv[5] = (short)f2bf(f1.y);
            wv[6] = (short)f2bf(f1.z); wv[7] = (short)f2bf(f1.w);
            *(short8*)(&wt[row][g * 8]) = wv;
        }
        // stage x quarter (coalesced): thread -> (row = tid>>4, 4 k-cols)
        {
            int row = tid >> 4, kc = (tid & 15) * 4;
            float4 xv = *(const float4*)(x + (size_t)(bid * 64 + row) * 256 + kp * 64 + kc);
            short4v s;
            s[0] = (short)f2bf(xv.x); s[1] = (short)f2bf(xv.y);
            s[2] = (short)f2bf(xv.z); s[3] = (short)f2bf(xv.w);
            *(short4v*)(&xs[row][kc]) = s;
        }
        __syncthreads();
#pragma unroll
        for (int ks = 0; ks < 2; ++ks) {
            short8 af = *(const short8*)(&xs[jg * 16 + t16][ks * 32 + q * 8]);
#pragma unroll
            for (int ct = 0; ct < 4; ++ct) {
                short8 bf = *(const short8*)(&wt[og * 64 + ct * 16 + t16][ks * 32 + q * 8]);
                acc[ct] = __builtin_amdgcn_mfma_f32_16x16x32_bf16(af, bf, acc[ct], 0, 0, 0);
            }
        }
    }

    // hT store: D col=t16 -> o_local, row=q*4+r -> j_local  (o-major layout)
    const int jbase = bid * 64 + jg * 16 + q * 4;   // flat b*2048+j
    const int b = jbase >> 11, jj = jbase & 2047;
#pragma unroll
    for (int ct = 0; ct < 4; ++ct) {
        const int o = og * 64 + ct * 16 + t16;
        short4v sv;
        sv[0] = (short)f2bf(acc[ct][0]);
        sv[1] = (short)f2bf(acc[ct][1]);
        sv[2] = (short)f2bf(acc[ct][2]);
        sv[3] = (short)f2bf(acc[ct][3]);
        *(short4v*)(hT + ((size_t)b * 256 + o) * 2048 + jj) = sv;
    }

    // s_src/s_dst partials (this wave's 64 o), 16-lane shuffle
    float psv[4] = {}, pdv[4] = {};
#pragma unroll
    for (int ct = 0; ct < 4; ++ct) {
        const int o = og * 64 + ct * 16 + t16;
        float as = a_src[o], ad = a_dst[o];
#pragma unroll
        for (int r = 0; r < 4; ++r) {
            psv[r] = __fmaf_rn(acc[ct][r], as, psv[r]);
            pdv[r] = __fmaf_rn(acc[ct][r], ad, pdv[r]);
        }
    }
#pragma unroll
    for (int m = 1; m < 16; m <<= 1) {
#pragma unroll
        for (int r = 0; r < 4; ++r) {
            psv[r] += __shfl_xor(psv[r], m);
            pdv[r] += __shfl_xor(pdv[r], m);
        }
    }
    if (t16 == 0) {
#pragma unroll
        for (int r = 0; r < 4; ++r) {
            sred[0][og][jg * 16 + q * 4 + r] = psv[r];
            sred[1][og][jg * 16 + q * 4 + r] = pdv[r];
        }
    }
    __syncthreads();
    if (tid < 64) {
        float ss = sred[0][0][tid] + sred[0][1][tid] + sred[0][2][tid] + sred[0][3][tid];
        float dd = sred[1][0][tid] + sred[1][1][tid] + sred[1][2][tid] + sred[1][3][tid];
        s_src[bid * 64 + tid] = ss;
        s_dst[bid * 64 + tid] = dd;
    }
}

// ---------------------------------------------------------------------------
// attn (R5/R7-verbatim, twice harness-passed, ~23us): bitmask + LDS-staged
// hT, 1 barrier/chunk, 32x32 wave tiles, 1024 threads, grid (8,32).
// ---------------------------------------------------------------------------
__global__ __launch_bounds__(1024) void attn(const ushort_t* __restrict__ hT,
                                             const u64_t* __restrict__ adjb,
                                             const float* __restrict__ s_src,
                                             const float* __restrict__ s_dst,
                                             float* __restrict__ out) {
    const int tid = threadIdx.x;           // 0..1023
    const int w = tid >> 6;                // wave 0..15
    const int lane = tid & 63;
    const int l5 = lane & 31, hi = lane >> 5;
    const int b = blockIdx.x;
    const int i0 = blockIdx.y * 64;

    __shared__ ushort_t hts[2][256][40];   // 256 o x 32 j (+8 pad) : 40 KB
    __shared__ ushort_t ps[2][64][40];     // 64 i x 32 j (+8 pad)  : 10 KB
    __shared__ float sdl[2048];            // s_dst * log2e : 8 KB
    __shared__ float rls[64];              // row sums of p

    // stage s_dst*log2e (2 floats/thread)
    const float* sdb = s_dst + (size_t)b * 2048;
    {
        int idx = tid * 2;
        float2 v = *(const float2*)(sdb + idx);
        v.x *= LOG2E; v.y *= LOG2E;
        *(float2*)(&sdl[idx]) = v;
    }

    // p-producer mapping: i = 4w + (lane>>4), j-pair = lane&15
    const int ip = w * 4 + (lane >> 4);
    const int jp = lane & 15;
    const float si = s_src[(size_t)b * 2048 + i0 + ip] * LOG2E;
    // bitmask row: 32 u64 words (as uint2), word it covers j in [it*64,+64)
    const uint2* amr = (const uint2*)(adjb + ((size_t)b * 2048 + i0 + ip) * 32);

    // hT stage mapping: row = tid>>2, 8-j segment = tid&3 (16 B/thread)
    const int hrow = tid >> 2, hseg = tid & 3;
    const ushort_t* hTg = hT + ((size_t)b * 256 + hrow) * 2048 + hseg * 8;

    // consumer mapping: wave tile 32 i x 32 o
    const int osub = (w & 7) * 32, ih = (w >> 3) * 32;

    floatx16 acc = {};
    float lsum = 0.f;
    int4 hreg;
    uint2 amc, amcN;

    // prologue: hT chunk 0; mask words for chunks 0,1
    hreg = *(const int4*)(hTg);
    amc = amr[0];
    __syncthreads();   // sdl ready

#pragma unroll 1
    for (int it = 0; it < 32; ++it) {
        const int c = it * 2;
        // ================= even chunk c (buf 0, mask amc.x) ================
        *(int4*)(&hts[0][hrow][hseg * 8]) = hreg;
        hreg = *(const int4*)(hTg + (size_t)(c + 1) * 32);        // prefetch c+1
        amcN = amr[(it + 1 < 32) ? it + 1 : 31];                  // prefetch masks
        {
            float2 sd = *(const float2*)(&sdl[c * 32 + jp * 2]);
            unsigned m0 = (amc.x >> (jp * 2)) & 1u;
            unsigned m1 = (amc.x >> (jp * 2 + 1)) & 1u;
            float t0 = si + sd.x;
            float t1 = si + sd.y;
            float l0 = fmaxf(t0, 0.2f * t0);
            float l1 = fmaxf(t1, 0.2f * t1);
            float p0 = __builtin_amdgcn_exp2f(l0);
            float p1 = __builtin_amdgcn_exp2f(l1);
            p0 = m0 ? p0 : 0.0f;
            p1 = m1 ? p1 : 0.0f;
            unsigned short u0 = f2bf(p0);
            unsigned short u1 = f2bf(p1);
            lsum += bf2f(u0) + bf2f(u1);
            *(unsigned*)(&ps[0][ip][jp * 2]) = (unsigned)u0 | ((unsigned)u1 << 16);
        }
        __syncthreads();
#pragma unroll
        for (int ks = 0; ks < 2; ++ks) {
            short8 afr = *(const short8*)(&hts[0][osub + l5][ks * 16 + hi * 8]);
            short8 bfr = *(const short8*)(&ps[0][ih + l5][ks * 16 + hi * 8]);
            acc = __builtin_amdgcn_mfma_f32_32x32x16_bf16(afr, bfr, acc, 0, 0, 0);
        }
        // ================= odd chunk c+1 (buf 1, mask amc.y) ===============
        *(int4*)(&hts[1][hrow][hseg * 8]) = hreg;
        {   // prefetch hT chunk c+2 (clamped in-bounds at tail)
            const int nh = (c + 2 < 64) ? c + 2 : 63;
            hreg = *(const int4*)(hTg + (size_t)nh * 32);
        }
        {
            float2 sd = *(const float2*)(&sdl[(c + 1) * 32 + jp * 2]);
            unsigned m0 = (amc.y >> (jp * 2)) & 1u;
            unsigned m1 = (amc.y >> (jp * 2 + 1)) & 1u;
            float t0 = si + sd.x;
            float t1 = si + sd.y;
            float l0 = fmaxf(t0, 0.2f * t0);
            float l1 = fmaxf(t1, 0.2f * t1);
            float p0 = __builtin_amdgcn_exp2f(l0);
            float p1 = __builtin_amdgcn_exp2f(l1);
            p0 = m0 ? p0 : 0.0f;
            p1 = m1 ? p1 : 0.0f;
            unsigned short u0 = f2bf(p0);
            unsigned short u1 = f2bf(p1);
            lsum += bf2f(u0) + bf2f(u1);
            *(unsigned*)(&ps[1][ip][jp * 2]) = (unsigned)u0 | ((unsigned)u1 << 16);
        }
        __syncthreads();
#pragma unroll
        for (int ks = 0; ks < 2; ++ks) {
            short8 afr = *(const short8*)(&hts[1][osub + l5][ks * 16 + hi * 8]);
            short8 bfr = *(const short8*)(&ps[1][ih + l5][ks * 16 + hi * 8]);
            acc = __builtin_amdgcn_mfma_f32_32x32x16_bf16(afr, bfr, acc, 0, 0, 0);
        }
        amc = amcN;
    }

    // row sums: row ip's full j-range lives in its 16 jp-lanes
#pragma unroll
    for (int m = 1; m < 16; m <<= 1) lsum += __shfl_xor(lsum, m);
    if (jp == 0) rls[ip] = lsum;
    __syncthreads();

    // epilogue: D col=l5 -> i_local, row=(reg&3)+8*(reg>>2)+4*hi -> o_local
    {
        const int i = ih + l5;
        const float s = rls[i];
        const float rl = (s > 0.f) ? 1.0f / s : 0.0f;
        float* orow = out + ((size_t)b * 2048 + i0 + i) * 256 + osub;
#pragma unroll
        for (int rq = 0; rq < 4; ++rq) {
            floatx4 v;
            v[0] = acc[rq * 4 + 0] * rl;
            v[1] = acc[rq * 4 + 1] * rl;
            v[2] = acc[rq * 4 + 2] * rl;
            v[3] = acc[rq * 4 + 3] * rl;
            *(floatx4*)(orow + rq * 8 + hi * 4) = v;
        }
    }
}

extern "C" void kernel_launch(void* const* d_in, const int* in_sizes, int n_in,
                              void* d_out, int out_size, void* d_ws, size_t ws_size,
                              hipStream_t stream) {
    const float* x     = (const float*)d_in[0];
    const int*   adj   = (const int*)d_in[1];
    const float* W     = (const float*)d_in[2];
    const float* a_src = (const float*)d_in[3];
    const float* a_dst = (const float*)d_in[4];
    float* out = (float*)d_out;

    // ws: hT 8MB | s_src 64KB | s_dst 64KB | adjb 4MB = 12.125MB (proven)
    char* ws = (char*)d_ws;
    ushort_t* hT = (ushort_t*)ws;                                   // [0, 8M)
    float* s_src = (float*)(ws + (size_t)8 * 1024 * 1024);          // 64 KB
    float* s_dst = s_src + 16384;                                   // 64 KB
    u64_t* adjb  = (u64_t*)(s_dst + 16384);                         // 4 MB

    prep<<<768, 1024, 0, stream>>>(x, W, adj, hT, a_src, a_dst, s_src, s_dst, adjb);
    attn<<<dim3(8, 32), 1024, 0, stream>>>(hT, adjb, s_src, s_dst, out);
}

// Round 9
// 244.576 us; speedup vs baseline: 1.2219x; 1.0832x over previous
//
#include <hip/hip_runtime.h>
#include <hip/hip_bf16.h>
#include <cstdint>
#include <cstddef>

typedef __attribute__((ext_vector_type(8))) short short8;
typedef __attribute__((ext_vector_type(4))) short short4v;
typedef __attribute__((ext_vector_type(4))) float floatx4;
typedef __attribute__((ext_vector_type(16))) float floatx16;
typedef unsigned short ushort_t;
typedef unsigned long long u64_t;

#define LOG2E 1.44269504088896340736f

__device__ __forceinline__ unsigned short f2bf(float f) {
    unsigned u = __float_as_uint(f);
    u += 0x7FFFu + ((u >> 16) & 1u);   // RNE
    return (unsigned short)(u >> 16);
}
__device__ __forceinline__ float bf2f(unsigned short s) {
    return __uint_as_float(((unsigned)s) << 16);
}

// ---------------------------------------------------------------------------
// prep: fused gemm_h + adj byte-pack.  Grid 1280 x 1024 threads.
//
// R8 lesson: ballot-based pack never exceeds ~2 TB/s effective (ballot ->
// SGPR pair + lane0 store serializes each wave to ~1 load/round-trip; 24
// resident waves/CU all waiting, VALUBusy 5%).  The harness fill kernel --
// lane-local stores only -- hits 6.9 TB/s on the same machine.  So the pack
// is now FULLY LANE-LOCAL: thread reads 8 consecutive ints (2x int4, dense
// 16B/lane), emits one mask byte (pure VALU), stores 1B (64B/wave dense).
// Byte b of adjb == flat adj bits [8b, 8b+8), little-endian-consistent with
// the u64 words attn reads.  No cross-lane ops anywhere.
//
// blocks [0,256):    gemm_h body (R7/R8-passing, byte-for-byte).
// blocks [256,1280): byte-pack, 4 bytes/thread at 1MB stride.
// ---------------------------------------------------------------------------
__global__ __launch_bounds__(1024, 8) void prep(const float* __restrict__ x,
                                                const float* __restrict__ W,
                                                const int* __restrict__ adj,
                                                ushort_t* __restrict__ hT,
                                                const float* __restrict__ a_src,
                                                const float* __restrict__ a_dst,
                                                float* __restrict__ s_src,
                                                float* __restrict__ s_dst,
                                                u64_t* __restrict__ adjb) {
    __shared__ ushort_t wt[256][72];   // W quarter: 256 o x 64 k (+8 pad)
    __shared__ ushort_t xs[64][72];    // x quarter: 64 j x 64 k (+8 pad)
    __shared__ float sred[2][4][64];

    const int tid = threadIdx.x;
    const int w = tid >> 6, lane = tid & 63;

    if (blockIdx.x >= 256) {
        // ------------- lane-local byte pack (1024 blocks) ------------------
        const size_t base = (size_t)(blockIdx.x - 256) * 1024 + tid;
        unsigned char* ab = (unsigned char*)adjb;
#pragma unroll
        for (int i = 0; i < 4; ++i) {
            const size_t bI = base + (size_t)i * (1024 * 1024);
            const int* ap = adj + bI * 8;
            int4 a0 = *(const int4*)(ap);
            int4 a1 = *(const int4*)(ap + 4);
            unsigned v = (a0.x != 0 ? 1u : 0u)   | (a0.y != 0 ? 2u : 0u)  |
                         (a0.z != 0 ? 4u : 0u)   | (a0.w != 0 ? 8u : 0u)  |
                         (a1.x != 0 ? 16u : 0u)  | (a1.y != 0 ? 32u : 0u) |
                         (a1.z != 0 ? 64u : 0u)  | (a1.w != 0 ? 128u : 0u);
            ab[bI] = (unsigned char)v;
        }
        return;
    }

    // ------------------- gemm half (256 blocks, R8 body) ------------------
    const int bid = blockIdx.x;
    const int q = (lane >> 4) & 3, t16 = lane & 15;
    const int jg = w >> 2, og = w & 3;

    floatx4 acc[4] = {};
#pragma unroll
    for (int kp = 0; kp < 4; ++kp) {
        if (kp) __syncthreads();       // protect wt/xs overwrite
        // stage W quarter (fp32 -> bf16), 16 ushorts/thread
#pragma unroll
        for (int r = 0; r < 2; ++r) {
            int G = tid + 1024 * r;
            int row = G >> 3, g = G & 7;
            const float* wsrc = W + (size_t)row * 256 + kp * 64 + g * 8;
            float4 f0 = *(const float4*)(wsrc);
            float4 f1 = *(const float4*)(wsrc + 4);
            short8 wv;
            wv[0] = (short)f2bf(f0.x); wv[1] = (short)f2bf(f0.y);
            wv[2] = (short)f2bf(f0.z); wv[3] = (short)f2bf(f0.w);
            wv[4] = (short)f2bf(f1.x); wv[5] = (short)f2bf(f1.y);
            wv[6] = (short)f2bf(f1.z); wv[7] = (short)f2bf(f1.w);
            *(short8*)(&wt[row][g * 8]) = wv;
        }
        // stage x quarter (coalesced): thread -> (row = tid>>4, 4 k-cols)
        {
            int row = tid >> 4, kc = (tid & 15) * 4;
            float4 xv = *(const float4*)(x + (size_t)(bid * 64 + row) * 256 + kp * 64 + kc);
            short4v s;
            s[0] = (short)f2bf(xv.x); s[1] = (short)f2bf(xv.y);
            s[2] = (short)f2bf(xv.z); s[3] = (short)f2bf(xv.w);
            *(short4v*)(&xs[row][kc]) = s;
        }
        __syncthreads();
#pragma unroll
        for (int ks = 0; ks < 2; ++ks) {
            short8 af = *(const short8*)(&xs[jg * 16 + t16][ks * 32 + q * 8]);
#pragma unroll
            for (int ct = 0; ct < 4; ++ct) {
                short8 bf = *(const short8*)(&wt[og * 64 + ct * 16 + t16][ks * 32 + q * 8]);
                acc[ct] = __builtin_amdgcn_mfma_f32_16x16x32_bf16(af, bf, acc[ct], 0, 0, 0);
            }
        }
    }

    // hT store: D col=t16 -> o_local, row=q*4+r -> j_local  (o-major layout)
    const int jbase = bid * 64 + jg * 16 + q * 4;   // flat b*2048+j
    const int b = jbase >> 11, jj = jbase & 2047;
#pragma unroll
    for (int ct = 0; ct < 4; ++ct) {
        const int o = og * 64 + ct * 16 + t16;
        short4v sv;
        sv[0] = (short)f2bf(acc[ct][0]);
        sv[1] = (short)f2bf(acc[ct][1]);
        sv[2] = (short)f2bf(acc[ct][2]);
        sv[3] = (short)f2bf(acc[ct][3]);
        *(short4v*)(hT + ((size_t)b * 256 + o) * 2048 + jj) = sv;
    }

    // s_src/s_dst partials (this wave's 64 o), 16-lane shuffle
    float psv[4] = {}, pdv[4] = {};
#pragma unroll
    for (int ct = 0; ct < 4; ++ct) {
        const int o = og * 64 + ct * 16 + t16;
        float as = a_src[o], ad = a_dst[o];
#pragma unroll
        for (int r = 0; r < 4; ++r) {
            psv[r] = __fmaf_rn(acc[ct][r], as, psv[r]);
            pdv[r] = __fmaf_rn(acc[ct][r], ad, pdv[r]);
        }
    }
#pragma unroll
    for (int m = 1; m < 16; m <<= 1) {
#pragma unroll
        for (int r = 0; r < 4; ++r) {
            psv[r] += __shfl_xor(psv[r], m);
            pdv[r] += __shfl_xor(pdv[r], m);
        }
    }
    if (t16 == 0) {
#pragma unroll
        for (int r = 0; r < 4; ++r) {
            sred[0][og][jg * 16 + q * 4 + r] = psv[r];
            sred[1][og][jg * 16 + q * 4 + r] = pdv[r];
        }
    }
    __syncthreads();
    if (tid < 64) {
        float ss = sred[0][0][tid] + sred[0][1][tid] + sred[0][2][tid] + sred[0][3][tid];
        float dd = sred[1][0][tid] + sred[1][1][tid] + sred[1][2][tid] + sred[1][3][tid];
        s_src[bid * 64 + tid] = ss;
        s_dst[bid * 64 + tid] = dd;
    }
}

// ---------------------------------------------------------------------------
// attn (R5/R7/R8-verbatim, thrice harness-passed, ~26us): bitmask +
// LDS-staged hT, 1 barrier/chunk, 32x32 wave tiles, 1024 threads, grid (8,32).
// ---------------------------------------------------------------------------
__global__ __launch_bounds__(1024) void attn(const ushort_t* __restrict__ hT,
                                             const u64_t* __restrict__ adjb,
                                             const float* __restrict__ s_src,
                                             const float* __restrict__ s_dst,
                                             float* __restrict__ out) {
    const int tid = threadIdx.x;           // 0..1023
    const int w = tid >> 6;                // wave 0..15
    const int lane = tid & 63;
    const int l5 = lane & 31, hi = lane >> 5;
    const int b = blockIdx.x;
    const int i0 = blockIdx.y * 64;

    __shared__ ushort_t hts[2][256][40];   // 256 o x 32 j (+8 pad) : 40 KB
    __shared__ ushort_t ps[2][64][40];     // 64 i x 32 j (+8 pad)  : 10 KB
    __shared__ float sdl[2048];            // s_dst * log2e : 8 KB
    __shared__ float rls[64];              // row sums of p

    // stage s_dst*log2e (2 floats/thread)
    const float* sdb = s_dst + (size_t)b * 2048;
    {
        int idx = tid * 2;
        float2 v = *(const float2*)(sdb + idx);
        v.x *= LOG2E; v.y *= LOG2E;
        *(float2*)(&sdl[idx]) = v;
    }

    // p-producer mapping: i = 4w + (lane>>4), j-pair = lane&15
    const int ip = w * 4 + (lane >> 4);
    const int jp = lane & 15;
    const float si = s_src[(size_t)b * 2048 + i0 + ip] * LOG2E;
    // bitmask row: 32 u64 words (as uint2), word it covers j in [it*64,+64)
    const uint2* amr = (const uint2*)(adjb + ((size_t)b * 2048 + i0 + ip) * 32);

    // hT stage mapping: row = tid>>2, 8-j segment = tid&3 (16 B/thread)
    const int hrow = tid >> 2, hseg = tid & 3;
    const ushort_t* hTg = hT + ((size_t)b * 256 + hrow) * 2048 + hseg * 8;

    // consumer mapping: wave tile 32 i x 32 o
    const int osub = (w & 7) * 32, ih = (w >> 3) * 32;

    floatx16 acc = {};
    float lsum = 0.f;
    int4 hreg;
    uint2 amc, amcN;

    // prologue: hT chunk 0; mask words for chunks 0,1
    hreg = *(const int4*)(hTg);
    amc = amr[0];
    __syncthreads();   // sdl ready

#pragma unroll 1
    for (int it = 0; it < 32; ++it) {
        const int c = it * 2;
        // ================= even chunk c (buf 0, mask amc.x) ================
        *(int4*)(&hts[0][hrow][hseg * 8]) = hreg;
        hreg = *(const int4*)(hTg + (size_t)(c + 1) * 32);        // prefetch c+1
        amcN = amr[(it + 1 < 32) ? it + 1 : 31];                  // prefetch masks
        {
            float2 sd = *(const float2*)(&sdl[c * 32 + jp * 2]);
            unsigned m0 = (amc.x >> (jp * 2)) & 1u;
            unsigned m1 = (amc.x >> (jp * 2 + 1)) & 1u;
            float t0 = si + sd.x;
            float t1 = si + sd.y;
            float l0 = fmaxf(t0, 0.2f * t0);
            float l1 = fmaxf(t1, 0.2f * t1);
            float p0 = __builtin_amdgcn_exp2f(l0);
            float p1 = __builtin_amdgcn_exp2f(l1);
            p0 = m0 ? p0 : 0.0f;
            p1 = m1 ? p1 : 0.0f;
            unsigned short u0 = f2bf(p0);
            unsigned short u1 = f2bf(p1);
            lsum += bf2f(u0) + bf2f(u1);
            *(unsigned*)(&ps[0][ip][jp * 2]) = (unsigned)u0 | ((unsigned)u1 << 16);
        }
        __syncthreads();
#pragma unroll
        for (int ks = 0; ks < 2; ++ks) {
            short8 afr = *(const short8*)(&hts[0][osub + l5][ks * 16 + hi * 8]);
            short8 bfr = *(const short8*)(&ps[0][ih + l5][ks * 16 + hi * 8]);
            acc = __builtin_amdgcn_mfma_f32_32x32x16_bf16(afr, bfr, acc, 0, 0, 0);
        }
        // ================= odd chunk c+1 (buf 1, mask amc.y) ===============
        *(int4*)(&hts[1][hrow][hseg * 8]) = hreg;
        {   // prefetch hT chunk c+2 (clamped in-bounds at tail)
            const int nh = (c + 2 < 64) ? c + 2 : 63;
            hreg = *(const int4*)(hTg + (size_t)nh * 32);
        }
        {
            float2 sd = *(const float2*)(&sdl[(c + 1) * 32 + jp * 2]);
            unsigned m0 = (amc.y >> (jp * 2)) & 1u;
            unsigned m1 = (amc.y >> (jp * 2 + 1)) & 1u;
            float t0 = si + sd.x;
            float t1 = si + sd.y;
            float l0 = fmaxf(t0, 0.2f * t0);
            float l1 = fmaxf(t1, 0.2f * t1);
            float p0 = __builtin_amdgcn_exp2f(l0);
            float p1 = __builtin_amdgcn_exp2f(l1);
            p0 = m0 ? p0 : 0.0f;
            p1 = m1 ? p1 : 0.0f;
            unsigned short u0 = f2bf(p0);
            unsigned short u1 = f2bf(p1);
            lsum += bf2f(u0) + bf2f(u1);
            *(unsigned*)(&ps[1][ip][jp * 2]) = (unsigned)u0 | ((unsigned)u1 << 16);
        }
        __syncthreads();
#pragma unroll
        for (int ks = 0; ks < 2; ++ks) {
            short8 afr = *(const short8*)(&hts[1][osub + l5][ks * 16 + hi * 8]);
            short8 bfr = *(const short8*)(&ps[1][ih + l5][ks * 16 + hi * 8]);
            acc = __builtin_amdgcn_mfma_f32_32x32x16_bf16(afr, bfr, acc, 0, 0, 0);
        }
        amc = amcN;
    }

    // row sums: row ip's full j-range lives in its 16 jp-lanes
#pragma unroll
    for (int m = 1; m < 16; m <<= 1) lsum += __shfl_xor(lsum, m);
    if (jp == 0) rls[ip] = lsum;
    __syncthreads();

    // epilogue: D col=l5 -> i_local, row=(reg&3)+8*(reg>>2)+4*hi -> o_local
    {
        const int i = ih + l5;
        const float s = rls[i];
        const float rl = (s > 0.f) ? 1.0f / s : 0.0f;
        float* orow = out + ((size_t)b * 2048 + i0 + i) * 256 + osub;
#pragma unroll
        for (int rq = 0; rq < 4; ++rq) {
            floatx4 v;
            v[0] = acc[rq * 4 + 0] * rl;
            v[1] = acc[rq * 4 + 1] * rl;
            v[2] = acc[rq * 4 + 2] * rl;
            v[3] = acc[rq * 4 + 3] * rl;
            *(floatx4*)(orow + rq * 8 + hi * 4) = v;
        }
    }
}

extern "C" void kernel_launch(void* const* d_in, const int* in_sizes, int n_in,
                              void* d_out, int out_size, void* d_ws, size_t ws_size,
                              hipStream_t stream) {
    const float* x     = (const float*)d_in[0];
    const int*   adj   = (const int*)d_in[1];
    const float* W     = (const float*)d_in[2];
    const float* a_src = (const float*)d_in[3];
    const float* a_dst = (const float*)d_in[4];
    float* out = (float*)d_out;

    // ws: hT 8MB | s_src 64KB | s_dst 64KB | adjb 4MB = 12.125MB (proven)
    char* ws = (char*)d_ws;
    ushort_t* hT = (ushort_t*)ws;                                   // [0, 8M)
    float* s_src = (float*)(ws + (size_t)8 * 1024 * 1024);          // 64 KB
    float* s_dst = s_src + 16384;                                   // 64 KB
    u64_t* adjb  = (u64_t*)(s_dst + 16384);                         // 4 MB

    prep<<<1280, 1024, 0, stream>>>(x, W, adj, hT, a_src, a_dst, s_src, s_dst, adjb);
    attn<<<dim3(8, 32), 1024, 0, stream>>>(hT, adjb, s_src, s_dst, out);
}